// Round 15
// baseline (379.164 us; speedup 1.0000x reference)
//
#include <hip/hip_runtime.h>

// ---------------------------------------------------------------------------
// InvariantPolynomial, round 17: split k_mid -> k_mid(p1+p2) + k_tab(p3).
//
// k_mid invariant at 180+-5us across FOUR structures -> per-phase model can't
// explain it; the untried lever is the intra-block barrier serialization of
// the 3 phases (grid 1250 ~ 4.9 blocks/CU, no cross-grid phase overlap).
// Split: k_mid = phases 1+2 only (phase 2 writes straight to global mid,
// smid LDS deleted -> LDS 13.1KB); k_tab = standalone phase 3 (256thr/4
// nodes, stages mid rows to LDS, writes the 4x64 tables IN PLACE over the
// first 256 floats of each mid row -> no new workspace). k_out reads
// mid[s*368 + zd*64 + lane]. Also: separate dispatch timings = the phase
// ablation measurement.
//
// ws layout (ints/floats):
//   counts  @ int   [0      , 20000)
//   start   @ int   [32768  , 52769)
//   cursor  @ int   [65536  , 85536)
//   csr     @ int   [98304  , 418304)   dst-CSR: s | q<<16 | (d&15)<<20
//   pos4    @ float [425984 , 505984)   20000 x 4
//   node_sh @ float [524288 , 764288)   20000 x 12 (9 used, inv_nn folded)
//   w2p     @ float [786432 , 851968)   16 x 64 x 64
//   mid     @ float [1048576, 8408576)  20000 x 368; after k_tab the first
//                                       256 of each row = tab[zd][64]
// ---------------------------------------------------------------------------

#define N_EDGES   320000
#define NN_NODES  20000
#define NN_GRAPHS 5000

__device__ __forceinline__ void sh_from_vec(float x, float y, float z,
                                            float* B1, float* B2) {
    const float s3   = 1.7320508075688772f;
    const float s15  = 3.8729833462074170f;
    const float s5h  = 1.1180339887498949f;
    const float s15h = 1.9364916731037085f;
    B1[0] = s3 * y; B1[1] = s3 * z; B1[2] = s3 * x;
    float r2 = x * x + y * y + z * z;
    B2[0] = s15 * x * y;
    B2[1] = s15 * y * z;
    B2[2] = s5h * (3.f * z * z - r2);
    B2[3] = s15 * x * z;
    B2[4] = s15h * (x * x - y * y);
}

// ------------------- zero + pos4 pack + w2p transpose ----------------------
__global__ __launch_bounds__(256) void k_zero(const float* __restrict__ pos,
                                              const float* __restrict__ w2,
                                              int* __restrict__ counts,
                                              float* __restrict__ out,
                                              float4* __restrict__ pos4,
                                              float* __restrict__ w2p) {
    int tid = blockIdx.x * blockDim.x + threadIdx.x;
    int stride = gridDim.x * blockDim.x;
    for (int i = tid; i < NN_NODES; i += stride) counts[i] = 0;
    for (int i = tid; i < NN_GRAPHS * 7; i += stride) out[i] = 0.f;
    for (int i = tid; i < NN_NODES; i += stride) {
        float4 p;
        p.x = pos[3 * i]; p.y = pos[3 * i + 1]; p.z = pos[3 * i + 2]; p.w = 0.f;
        pos4[i] = p;
    }
    const float cT0f =  0.02830690f;
    const float cT1f = -0.02635231f;
    const float cT2f = -0.01634300f;
    const float cT3f =  0.01265893f;
    const float cT4f =  0.02041241f;
    for (int idx = tid; idx < 16 * 64 * 64; idx += stride) {
        int jj = idx & 63;
        int u  = (idx >> 6) & 63;
        int q  = idx >> 12;
        float v = 0.f;
        if (jj < 6) {
            v = cT0f * w2[(u * 16 + q) * 6 + jj];
        } else if (jj < 9) {
            if (u < 24) v = cT1f * w2[6144 + u * 16 + q];
        } else if (jj < 27) {
            int w = (jj - 9) % 6;
            if (u < 24) v = cT2f * w2[6528 + (u * 16 + q) * 6 + w];
        } else if (jj < 57) {
            int w = (jj - 27) % 6;
            if (u < 16) v = cT3f * w2[8832 + (u * 16 + q) * 6 + w];
        } else if (jj < 62) {
            if (u < 16) v = cT4f * w2[10368 + u * 16 + q];
        }
        w2p[idx] = v;
    }
}

// --------------------------- histogram -------------------------------------
__global__ __launch_bounds__(256) void k_hist(const int* __restrict__ edst,
                                              int* __restrict__ counts) {
    int e = blockIdx.x * blockDim.x + threadIdx.x;
    if (e < N_EDGES) atomicAdd(&counts[edst[e]], 1);
}

// ------------------ exclusive scan: wave-shuffle version -------------------
__global__ __launch_bounds__(1024) void k_scan(const int* __restrict__ counts,
                                               int* __restrict__ start,
                                               int* __restrict__ cursor) {
    __shared__ int wsum[16];
    __shared__ int carry;
    __shared__ int tot;
    int tid = threadIdx.x;
    int wave = tid >> 6;
    int lane = tid & 63;
    if (tid == 0) carry = 0;
    __syncthreads();
    for (int base = 0; base < NN_NODES; base += 1024) {
        int i = base + tid;
        int v = (i < NN_NODES) ? counts[i] : 0;
        int x = v;
#pragma unroll
        for (int off = 1; off < 64; off <<= 1) {
            int y = __shfl_up(x, off, 64);
            if (lane >= off) x += y;
        }
        if (lane == 63) wsum[wave] = x;
        __syncthreads();
        if (tid < 16) {
            int w = wsum[tid];
            int xx = w;
#pragma unroll
            for (int off = 1; off < 16; off <<= 1) {
                int y = __shfl_up(xx, off, 64);
                if (tid >= off) xx += y;
            }
            wsum[tid] = xx - w;            // exclusive wave offset
            if (tid == 15) tot = xx;       // chunk total
        }
        __syncthreads();
        int excl = carry + wsum[wave] + x - v;
        if (i < NN_NODES) {
            start[i] = excl;
            cursor[i] = excl;
        }
        __syncthreads();
        if (tid == 0) carry += tot;
        __syncthreads();
    }
    if (tid == 0) start[NN_NODES] = carry;   // = N_EDGES
}

// --------------------------- dst-CSR fill ----------------------------------
__global__ __launch_bounds__(256) void k_fill(const int* __restrict__ esrc,
                                              const int* __restrict__ edst,
                                              const int* __restrict__ zarr,
                                              int* __restrict__ cursor,
                                              int* __restrict__ csr) {
    int e = blockIdx.x * blockDim.x + threadIdx.x;
    if (e >= N_EDGES) return;
    int d = edst[e];
    int s = esrc[e];
    int q = 4 * zarr[s] + zarr[d];
    int p = atomicAdd(&cursor[d], 1);
    csr[p] = s | (q << 16) | ((d & 15) << 20);
}

// ------------------- node_sh: edge-parallel, 16 nodes/block ----------------
__global__ __launch_bounds__(256) void k_nodesh(const float4* __restrict__ pos4,
                                                const int* __restrict__ start,
                                                const int* __restrict__ csr,
                                                float* __restrict__ node_sh) {
    __shared__ float ns[16][12];
    int t = threadIdx.x;
    if (t < 192) ns[t / 12][t % 12] = 0.f;
    __syncthreads();
    int nbase = blockIdx.x * 16;
    int e0 = start[nbase], e1 = start[nbase + 16];
    for (int idx = e0 + t; idx < e1; idx += 256) {
        int pk = csr[idx];
        int s = pk & 0xFFFF;
        int r = (pk >> 20) & 15;
        float4 pd = pos4[nbase + r];
        float4 ps = pos4[s];
        float x = ps.x - pd.x;
        float y = ps.y - pd.y;
        float z = ps.z - pd.z;
        float B1[3], B2[5];
        sh_from_vec(x, y, z, B1, B2);
        float* nr = &ns[r][0];
        atomicAdd(nr + 0, 1.f);
        atomicAdd(nr + 1, B1[0]); atomicAdd(nr + 2, B1[1]); atomicAdd(nr + 3, B1[2]);
        atomicAdd(nr + 4, B2[0]); atomicAdd(nr + 5, B2[1]); atomicAdd(nr + 6, B2[2]);
        atomicAdd(nr + 7, B2[3]); atomicAdd(nr + 8, B2[4]);
    }
    __syncthreads();
    if (t < 144) {
        int r = t / 9, c = t % 9;
        const float inv_nn = 0.57735026918962576f;
        node_sh[(size_t)(nbase + r) * 12 + c] = ns[r][c] * inv_nn;
    }
}

// ---- phase-2 pass, statically instantiated; writes GLOBAL mid rows --------
template<int RB>
__device__ __forceinline__ void phase2_pass(const float* __restrict__ Gl,
                                            float* __restrict__ mid,
                                            int nbase,
                                            const float* __restrict__ w1,
                                            int zpack, int j) {
    const int zp = zpack >> (2 * RB);
    float acc[8] = {0.f, 0.f, 0.f, 0.f, 0.f, 0.f, 0.f, 0.f};
    if (j < 64) {
        int w = j;
        for (int q = 0; q < 16; q++) {
            float wa = w1[q * 64 + w];
            float wb = w1[2048 + q * 64 + w];
            float wc = w1[5248 + q * 64 + w];
            int zdq = q & 3;
            const float* Gq = Gl + (q >> 2) * 51;
#pragma unroll
            for (int r2 = 0; r2 < 8; r2++) {
                if (((zp >> (2 * r2)) & 3) == zdq) {
                    const float* gq = Gq + (RB + r2) * 204;
                    acc[r2] += gq[0] * wa + gq[12] * wb + gq[42] * wc;
                }
            }
        }
#pragma unroll
        for (int r2 = 0; r2 < 8; r2++)
            mid[(size_t)(nbase + RB + r2) * 368 + j] = 0.33333333333333333f * acc[r2];
    } else if (j < 136) {
        int tt = j - 64, w = tt / 3, k = tt - 3 * w;
        for (int q = 0; q < 16; q++) {
            float wa = w1[3072 + q * 24 + w];
            float wb = w1[6272 + q * 24 + w];
            int zdq = q & 3;
            const float* Gq = Gl + (q >> 2) * 51;
#pragma unroll
            for (int r2 = 0; r2 < 8; r2++) {
                if (((zp >> (2 * r2)) & 3) == zdq) {
                    const float* gq = Gq + (RB + r2) * 204;
                    acc[r2] += gq[13 + k] * wa + gq[43 + k] * wb;
                }
            }
        }
#pragma unroll
        for (int r2 = 0; r2 < 8; r2++)
            mid[(size_t)(nbase + RB + r2) * 368 + j] = 0.70710678118654752f * acc[r2];
    } else if (j < 208) {
        int tt = j - 136, w = tt / 3, k = tt - 3 * w;
        for (int q = 0; q < 16; q++) {
            float wa = w1[1024 + q * 24 + w];
            float wb = w1[1664 + q * 24 + w];
            float wc = w1[3712 + q * 24 + w];
            float wd = w1[4608 + q * 24 + w];
            int zdq = q & 3;
            const float* Gq = Gl + (q >> 2) * 51;
#pragma unroll
            for (int r2 = 0; r2 < 8; r2++) {
                if (((zp >> (2 * r2)) & 3) == zdq) {
                    const float* gq = Gq + (RB + r2) * 204;
                    acc[r2] += gq[1 + k] * wa + gq[9 + k] * wb +
                               gq[21 + k] * wc + gq[34 + k] * wd;
                }
            }
        }
#pragma unroll
        for (int r2 = 0; r2 < 8; r2++)
            mid[(size_t)(nbase + RB + r2) * 368 + j] = 0.5f * acc[r2];
    } else if (j < 288) {
        int tt = j - 208, w = tt / 5, k = tt - 5 * w;
        for (int q = 0; q < 16; q++) {
            float wa = w1[1408 + q * 16 + w];
            float wb = w1[3456 + q * 16 + w];
            float wc = w1[4352 + q * 16 + w];
            float wd = w1[6656 + q * 16 + w];
            int zdq = q & 3;
            const float* Gq = Gl + (q >> 2) * 51;
#pragma unroll
            for (int r2 = 0; r2 < 8; r2++) {
                if (((zp >> (2 * r2)) & 3) == zdq) {
                    const float* gq = Gq + (RB + r2) * 204;
                    acc[r2] += gq[4 + k] * wa + gq[16 + k] * wb +
                               gq[29 + k] * wc + gq[46 + k] * wd;
                }
            }
        }
#pragma unroll
        for (int r2 = 0; r2 < 8; r2++)
            mid[(size_t)(nbase + RB + r2) * 368 + j] = 0.64549722436790280f * acc[r2];
    } else if (j < 368) {
        int tt = j - 288, w = tt / 5, k = tt - 5 * w;
        for (int q = 0; q < 16; q++) {
            float wa = w1[4096 + q * 16 + w];
            float wb = w1[4992 + q * 16 + w];
            int zdq = q & 3;
            const float* Gq = Gl + (q >> 2) * 51;
#pragma unroll
            for (int r2 = 0; r2 < 8; r2++) {
                if (((zp >> (2 * r2)) & 3) == zdq) {
                    const float* gq = Gq + (RB + r2) * 204;
                    acc[r2] += gq[24 + k] * wa + gq[37 + k] * wb;
                }
            }
        }
#pragma unroll
        for (int r2 = 0; r2 < 8; r2++)
            mid[(size_t)(nbase + RB + r2) * 368 + j] = 0.91287092917527690f * acc[r2];
    }
}

// ---------- fused TP1 -> mid (GLOBAL); phases 1+2 only; LDS 13.1KB ---------
__global__ __launch_bounds__(512, 4) void k_mid(const float4* __restrict__ pos4,
                                                const float* __restrict__ node_sh,
                                                const int* __restrict__ start,
                                                const int* __restrict__ csr,
                                                const float* __restrict__ w1,
                                                const int* __restrict__ zarr,
                                                float* __restrict__ mid) {
    __shared__ float Gl[16 * 204];         // [r][zs][51]
    __shared__ int szl[16];
    int t = threadIdx.x;
    int nbase = blockIdx.x * 16;
    for (int i = t; i < 16 * 204; i += 512) Gl[i] = 0.f;
    if (t < 16) szl[t] = zarr[nbase + t];
    __syncthreads();

    int e0 = start[nbase], e1 = start[nbase + 16];

    const float r3  = 0.57735026918962576f;
    const float r5  = 0.44721359549995794f;
    const float r6  = 0.40824829046386302f;
    const float r10 = 0.31622776601683794f;
    const float s30 = 0.18257418583505536f;
    const float rt3 = 1.7320508075688772f;
    const float c222 = 0.58554004376911990f;
    const float q6 = 0.40824829046386302f;
    const float h6 = 0.20412414523193151f;
    const float h2 = 0.35355339059327376f;
    const float r2c = 0.70710678118654752f;

    for (int idx = e0 + t; idx < e1; idx += 512) {
        int pk = csr[idx];
        int s = pk & 0xFFFF;
        int zs = (pk >> 18) & 3;           // q>>2 = z_src
        int r = (pk >> 20) & 15;
        float4 pd = pos4[nbase + r];
        float4 ps = pos4[s];
        float x = ps.x - pd.x;
        float y = ps.y - pd.y;
        float z = ps.z - pd.z;
        float B1[3], B2[5];
        sh_from_vec(x, y, z, B1, B2);
        const float4 nv0 = *(const float4*)(node_sh + s * 12);
        const float4 nv1 = *(const float4*)(node_sh + s * 12 + 4);
        float a0 = nv0.x;
        float A1[3] = {nv0.y, nv0.z, nv0.w};
        float A2[5] = {nv1.x, nv1.y, nv1.z, nv1.w, node_sh[s * 12 + 8]};
        float* gr = Gl + r * 204 + zs * 51;

        atomicAdd(gr + 0, a0);
        atomicAdd(gr + 1, a0 * B1[0] * r3);
        atomicAdd(gr + 2, a0 * B1[1] * r3);
        atomicAdd(gr + 3, a0 * B1[2] * r3);
        atomicAdd(gr + 4, a0 * B2[0] * r5);
        atomicAdd(gr + 5, a0 * B2[1] * r5);
        atomicAdd(gr + 6, a0 * B2[2] * r5);
        atomicAdd(gr + 7, a0 * B2[3] * r5);
        atomicAdd(gr + 8, a0 * B2[4] * r5);
        atomicAdd(gr + 9,  A1[0] * r3);
        atomicAdd(gr + 10, A1[1] * r3);
        atomicAdd(gr + 11, A1[2] * r3);
        atomicAdd(gr + 12, -r3 * (A1[0] * B1[0] + A1[1] * B1[1] + A1[2] * B1[2]));
        atomicAdd(gr + 13, -r6 * (A1[1] * B1[2] - A1[2] * B1[1]));
        atomicAdd(gr + 14, -r6 * (A1[2] * B1[0] - A1[0] * B1[2]));
        atomicAdd(gr + 15, -r6 * (A1[0] * B1[1] - A1[1] * B1[0]));
        atomicAdd(gr + 16, r10 * (A1[0] * B1[2] + A1[2] * B1[0]));
        atomicAdd(gr + 17, r10 * (A1[0] * B1[1] + A1[1] * B1[0]));
        atomicAdd(gr + 18, s30 * (2.f * A1[1] * B1[1] - A1[0] * B1[0] - A1[2] * B1[2]));
        atomicAdd(gr + 19, r10 * (A1[1] * B1[2] + A1[2] * B1[1]));
        atomicAdd(gr + 20, r10 * (A1[2] * B1[2] - A1[0] * B1[0]));
        {
            float Byy = -B2[2] * q6 - B2[4] * r2c;
            float Bzz = 2.f * B2[2] * q6;
            float Bxx = -B2[2] * q6 + B2[4] * r2c;
            float Bxy = B2[0] * r2c;
            float Byz = B2[1] * r2c;
            float Bxz = B2[3] * r2c;
            atomicAdd(gr + 21, -r5 * (Byy * A1[0] + Byz * A1[1] + Bxy * A1[2]));
            atomicAdd(gr + 22, -r5 * (Byz * A1[0] + Bzz * A1[1] + Bxz * A1[2]));
            atomicAdd(gr + 23, -r5 * (Bxy * A1[0] + Bxz * A1[1] + Bxx * A1[2]));
        }
        atomicAdd(gr + 24, -s30 * (B2[1] * A1[0] - B2[3] * A1[2] + 2.f * B2[4] * A1[1]));
        atomicAdd(gr + 25, -s30 * (-B2[0] * A1[0] - rt3 * B2[2] * A1[2] + B2[3] * A1[1] - B2[4] * A1[2]));
        atomicAdd(gr + 26, -s30 * (rt3 * B2[1] * A1[2] - rt3 * B2[3] * A1[0]));
        atomicAdd(gr + 27, -s30 * (B2[0] * A1[2] - B2[1] * A1[1] + rt3 * B2[2] * A1[0] - B2[4] * A1[0]));
        atomicAdd(gr + 28, -s30 * (-2.f * B2[0] * A1[1] + B2[1] * A1[2] + B2[3] * A1[0]));
        atomicAdd(gr + 29, A2[0] * r5);
        atomicAdd(gr + 30, A2[1] * r5);
        atomicAdd(gr + 31, A2[2] * r5);
        atomicAdd(gr + 32, A2[3] * r5);
        atomicAdd(gr + 33, A2[4] * r5);
        {
            float Ayy = -A2[2] * q6 - A2[4] * r2c;
            float Azz = 2.f * A2[2] * q6;
            float Axx = -A2[2] * q6 + A2[4] * r2c;
            float Axy = A2[0] * r2c;
            float Ayz = A2[1] * r2c;
            float Axz = A2[3] * r2c;
            atomicAdd(gr + 34, -r5 * (Ayy * B1[0] + Ayz * B1[1] + Axy * B1[2]));
            atomicAdd(gr + 35, -r5 * (Ayz * B1[0] + Azz * B1[1] + Axz * B1[2]));
            atomicAdd(gr + 36, -r5 * (Axy * B1[0] + Axz * B1[1] + Axx * B1[2]));
        }
        atomicAdd(gr + 37, s30 * (A2[1] * B1[0] - A2[3] * B1[2] + 2.f * A2[4] * B1[1]));
        atomicAdd(gr + 38, s30 * (-A2[0] * B1[0] - rt3 * A2[2] * B1[2] + A2[3] * B1[1] - A2[4] * B1[2]));
        atomicAdd(gr + 39, s30 * (rt3 * A2[1] * B1[2] - rt3 * A2[3] * B1[0]));
        atomicAdd(gr + 40, s30 * (A2[0] * B1[2] - A2[1] * B1[1] + rt3 * A2[2] * B1[0] - A2[4] * B1[0]));
        atomicAdd(gr + 41, s30 * (-2.f * A2[0] * B1[1] + A2[1] * B1[2] + A2[3] * B1[0]));
        atomicAdd(gr + 42, r5 * (A2[0] * B2[0] + A2[1] * B2[1] + A2[2] * B2[2] +
                                 A2[3] * B2[3] + A2[4] * B2[4]));
        atomicAdd(gr + 43, s30 * (-A2[0] * B2[1] + A2[1] * B2[0] +
                                  rt3 * (A2[2] * B2[3] - A2[3] * B2[2]) +
                                  A2[3] * B2[4] - A2[4] * B2[3]));
        atomicAdd(gr + 44, s30 * (-2.f * A2[0] * B2[4] + 2.f * A2[4] * B2[0] -
                                  A2[1] * B2[3] + A2[3] * B2[1]));
        atomicAdd(gr + 45, s30 * (A2[0] * B2[3] - A2[3] * B2[0] +
                                  rt3 * (A2[1] * B2[2] - A2[2] * B2[1]) +
                                  A2[1] * B2[4] - A2[4] * B2[1]));
        atomicAdd(gr + 46, -c222 * (-q6 * (A2[0] * B2[2] + A2[2] * B2[0]) +
                                    h2 * (A2[1] * B2[3] + A2[3] * B2[1])));
        atomicAdd(gr + 47, -c222 * (h6 * (A2[1] * B2[2] + A2[2] * B2[1]) -
                                    h2 * (A2[1] * B2[4] + A2[4] * B2[1]) +
                                    h2 * (A2[0] * B2[3] + A2[3] * B2[0])));
        atomicAdd(gr + 48, -c222 * (q6 * (A2[2] * B2[2] - A2[0] * B2[0] - A2[4] * B2[4]) +
                                    h6 * (A2[1] * B2[1] + A2[3] * B2[3])));
        atomicAdd(gr + 49, -c222 * (h6 * (A2[3] * B2[2] + A2[2] * B2[3]) +
                                    h2 * (A2[3] * B2[4] + A2[4] * B2[3]) +
                                    h2 * (A2[0] * B2[1] + A2[1] * B2[0])));
        atomicAdd(gr + 50, -c222 * (-q6 * (A2[4] * B2[2] + A2[2] * B2[4]) +
                                    h2 * (A2[3] * B2[3] - A2[1] * B2[1])));
    }
    __syncthreads();

    // Pack all 16 node z-values into ONE scalar (2 bits each).
    int zpack = 0;
#pragma unroll
    for (int r2 = 0; r2 < 16; r2++)
        zpack |= __builtin_amdgcn_readfirstlane(szl[r2]) << (2 * r2);

    // Phase 2: two STATIC passes, writing global mid rows.
    phase2_pass<0>(Gl, mid, nbase, w1, zpack, t);
    phase2_pass<8>(Gl, mid, nbase, w1, zpack, t);
}

// -------- standalone phase 3: mid rows -> in-place 4x64 tables -------------
// 256 thr = 4 waves = 4 nodes/block, grid 5000. Stage rows to LDS, compute,
// overwrite first 256 floats of each row.
__global__ __launch_bounds__(256, 8) void k_tab(const int* __restrict__ zarr,
                                                const float* __restrict__ w2p,
                                                float* __restrict__ mid) {
    __shared__ float srow[4][368];
    int t = threadIdx.x;
    int nbase = blockIdx.x * 4;
    for (int i = t; i < 4 * 368; i += 256) {
        int r = i / 368, c = i - r * 368;
        srow[r][c] = mid[(size_t)(nbase + r) * 368 + c];
    }
    __syncthreads();

    int wave = t >> 6;
    int lane = t & 63;
    int n = nbase + wave;
    int zs = zarr[n];
    int mbase, mstride, ulim;
    if (lane < 6)       { mbase = 0;                mstride = 1; ulim = 64; }
    else if (lane < 9)  { mbase = 64 + (lane - 6);  mstride = 3; ulim = 24; }
    else if (lane < 27) { mbase = 136 + (lane - 9) / 6;  mstride = 3; ulim = 24; }
    else if (lane < 57) { mbase = 208 + (lane - 27) / 6; mstride = 5; ulim = 16; }
    else if (lane < 62) { mbase = 288 + (lane - 57);     mstride = 5; ulim = 16; }
    else                { mbase = 0;                mstride = 0; ulim = 1; }
    int ulim1 = ulim - 1;
    const float* mr = &srow[wave][0];
    const float* wp = w2p + (size_t)(4 * zs) * 4096 + lane;
    float a0 = 0.f, a1 = 0.f, a2 = 0.f, a3 = 0.f;
#pragma unroll 4
    for (int u = 0; u < 64; u++) {
        int um = (u < ulim) ? u : ulim1;
        float m = mr[mbase + mstride * um];
        a0 += m * wp[u * 64];
        a1 += m * wp[4096 + u * 64];
        a2 += m * wp[8192 + u * 64];
        a3 += m * wp[12288 + u * 64];
    }
    float* trow = mid + (size_t)n * 368;
    trow[lane]       = a0;
    trow[64 + lane]  = a1;
    trow[128 + lane] = a2;
    trow[192 + lane] = a3;
}

// ---------------- TP2 + graph reduce: dst-major, 2-way unrolled ------------
__global__ __launch_bounds__(512, 8) void k_out(const float4* __restrict__ pos4,
                                                const int* __restrict__ zarr,
                                                const int* __restrict__ batch,
                                                const int* __restrict__ start,
                                                const int* __restrict__ csr,
                                                const float* __restrict__ tab,
                                                float* __restrict__ out) {
    int wave = threadIdx.x >> 6;
    int lane = threadIdx.x & 63;
    int n = blockIdx.x * 8 + wave;       // dst node
    float4 pd = pos4[n];
    int zd = zarr[n];
    int s0 = start[n], s1 = start[n + 1];

    int fsel, oidx;
    if (lane < 6)       { fsel = 0;                  oidx = lane + 1; }
    else if (lane < 9)  { fsel = 1 + (lane - 6);     oidx = 0; }
    else if (lane < 27) { fsel = 1 + (lane - 9) / 6; oidx = (lane - 9) % 6 + 1; }
    else if (lane < 57) { fsel = 4 + (lane - 27) / 6; oidx = (lane - 27) % 6 + 1; }
    else if (lane < 62) { fsel = 4 + (lane - 57);    oidx = 0; }
    else                { fsel = -1;                 oidx = 7; }
    float f0 = (fsel == 0) ? 1.f : 0.f;
    float f1 = (fsel == 1) ? 1.f : 0.f;
    float f2 = (fsel == 2) ? 1.f : 0.f;
    float f3 = (fsel == 3) ? 1.f : 0.f;
    float f4 = (fsel == 4) ? 1.f : 0.f;
    float f5 = (fsel == 5) ? 1.f : 0.f;
    float f6 = (fsel == 6) ? 1.f : 0.f;
    float f7 = (fsel == 7) ? 1.f : 0.f;
    float f8 = (fsel == 8) ? 1.f : 0.f;

    int zoff = zd * 64 + lane;
    float acc = 0.f;
    int idx = s0;
    for (; idx + 1 < s1; idx += 2) {
        int pkA = __builtin_amdgcn_readfirstlane(csr[idx]);
        int pkB = __builtin_amdgcn_readfirstlane(csr[idx + 1]);
        int sA = pkA & 0xFFFF;
        int sB = pkB & 0xFFFF;
        float TA = tab[(size_t)sA * 368 + zoff];
        float TB = tab[(size_t)sB * 368 + zoff];
        float4 psA = pos4[sA];
        float4 psB = pos4[sB];
        float xA = psA.x - pd.x, yA = psA.y - pd.y, zA = psA.z - pd.z;
        float xB = psB.x - pd.x, yB = psB.y - pd.y, zB = psB.z - pd.z;
        float B1A[3], B2A[5], B1B[3], B2B[5];
        sh_from_vec(xA, yA, zA, B1A, B2A);
        sh_from_vec(xB, yB, zB, B1B, B2B);
        float fA = f0 + f1 * B1A[0] + f2 * B1A[1] + f3 * B1A[2]
                 + f4 * B2A[0] + f5 * B2A[1] + f6 * B2A[2]
                 + f7 * B2A[3] + f8 * B2A[4];
        float fB = f0 + f1 * B1B[0] + f2 * B1B[1] + f3 * B1B[2]
                 + f4 * B2B[0] + f5 * B2B[1] + f6 * B2B[2]
                 + f7 * B2B[3] + f8 * B2B[4];
        acc += TA * fA + TB * fB;
    }
    if (idx < s1) {
        int pk = __builtin_amdgcn_readfirstlane(csr[idx]);
        int s = pk & 0xFFFF;
        float T = tab[(size_t)s * 368 + zoff];
        float4 ps = pos4[s];
        float x = ps.x - pd.x, y = ps.y - pd.y, z = ps.z - pd.z;
        float B1[3], B2[5];
        sh_from_vec(x, y, z, B1, B2);
        float factor = f0 + f1 * B1[0] + f2 * B1[1] + f3 * B1[2]
                     + f4 * B2[0] + f5 * B2[1] + f6 * B2[2]
                     + f7 * B2[3] + f8 * B2[4];
        acc += T * factor;
    }

    float ov[7];
#pragma unroll
    for (int w = 0; w < 7; w++) ov[w] = (oidx == w) ? acc : 0.f;
#pragma unroll
    for (int off = 32; off > 0; off >>= 1)
#pragma unroll
        for (int w = 0; w < 7; w++) ov[w] += __shfl_down(ov[w], off, 64);
    if (lane == 0) {
        float* og = out + batch[n] * 7;
#pragma unroll
        for (int w = 0; w < 7; w++) atomicAdd(og + w, ov[w]);
    }
}

// ---------------------------------------------------------------------------
extern "C" void kernel_launch(void* const* d_in, const int* in_sizes, int n_in,
                              void* d_out, int out_size, void* d_ws, size_t ws_size,
                              hipStream_t stream) {
    const float* pos  = (const float*)d_in[0];
    const int*   z    = (const int*)d_in[1];
    const int*   bat  = (const int*)d_in[2];
    const int*   esrc = (const int*)d_in[3];
    const int*   edst = (const int*)d_in[4];
    const float* w1   = (const float*)d_in[5];
    const float* w2   = (const float*)d_in[6];
    float* out = (float*)d_out;

    int*   wsI = (int*)d_ws;
    float* wsF = (float*)d_ws;
    int* counts  = wsI + 0;
    int* start   = wsI + 32768;
    int* cursor  = wsI + 65536;
    int* csr     = wsI + 98304;
    float4* pos4   = (float4*)(wsF + 425984);
    float* node_sh = wsF + 524288;
    float* w2p     = wsF + 786432;
    float* mid     = wsF + 1048576;

    k_zero<<<128, 256, 0, stream>>>(pos, w2, counts, out, pos4, w2p);
    k_hist<<<(N_EDGES + 255) / 256, 256, 0, stream>>>(edst, counts);
    k_scan<<<1, 1024, 0, stream>>>(counts, start, cursor);
    k_fill<<<(N_EDGES + 255) / 256, 256, 0, stream>>>(esrc, edst, z, cursor, csr);
    k_nodesh<<<NN_NODES / 16, 256, 0, stream>>>(pos4, start, csr, node_sh);
    k_mid<<<NN_NODES / 16, 512, 0, stream>>>(pos4, node_sh, start, csr, w1, z, mid);
    k_tab<<<NN_NODES / 4, 256, 0, stream>>>(z, w2p, mid);
    k_out<<<NN_NODES / 8, 512, 0, stream>>>(pos4, z, bat, start, csr, mid, out);
}

// Round 16
// 342.364 us; speedup vs baseline: 1.1075x; 1.1075x over previous
//
#include <hip/hip_runtime.h>

// ---------------------------------------------------------------------------
// InvariantPolynomial, round 18: revert split; de-contend phase-1 atomics.
//
// Round-17 split measured p1+p2 = 154us standalone (phase 3 ~30us) but cost
// +25us overhead -> reverted to round-16 fused structure (354us best).
// Remaining hypothesis for the invariant ~150us: 51 LDS atomics/edge with
// SAME-ADDRESS serialization (consecutive CSR slots share dst -> a wave's
// lanes hit ~2-4 G-cells; ds_add RMW serializes per address; invisible to
// VALUBusy and SQ_LDS_BANK_CONFLICT). Fix: strided lane mapping
// idx = e0 + wave + lane*8 (step 512) -> lanes span ~all 16 nodes ->
// same-address depth ~2-4. Same in k_nodesh (lane*4, step 256).
//
// ws layout (ints/floats):
//   counts  @ int   [0      , 20000)
//   start   @ int   [32768  , 52769)
//   cursor  @ int   [65536  , 85536)
//   csr     @ int   [98304  , 418304)   dst-CSR: s | q<<16 | (d&15)<<20
//   pos4    @ float [425984 , 505984)   20000 x 4
//   node_sh @ float [524288 , 764288)   20000 x 12 (9 used, inv_nn folded)
//   w2p     @ float [786432 , 851968)   16 x 64 x 64
//   tab     @ float [1048576, 6168576)  20000 x 4 x 64
// ---------------------------------------------------------------------------

#define N_EDGES   320000
#define NN_NODES  20000
#define NN_GRAPHS 5000

__device__ __forceinline__ void sh_from_vec(float x, float y, float z,
                                            float* B1, float* B2) {
    const float s3   = 1.7320508075688772f;
    const float s15  = 3.8729833462074170f;
    const float s5h  = 1.1180339887498949f;
    const float s15h = 1.9364916731037085f;
    B1[0] = s3 * y; B1[1] = s3 * z; B1[2] = s3 * x;
    float r2 = x * x + y * y + z * z;
    B2[0] = s15 * x * y;
    B2[1] = s15 * y * z;
    B2[2] = s5h * (3.f * z * z - r2);
    B2[3] = s15 * x * z;
    B2[4] = s15h * (x * x - y * y);
}

// ------------------- zero + pos4 pack + w2p transpose ----------------------
__global__ __launch_bounds__(256) void k_zero(const float* __restrict__ pos,
                                              const float* __restrict__ w2,
                                              int* __restrict__ counts,
                                              float* __restrict__ out,
                                              float4* __restrict__ pos4,
                                              float* __restrict__ w2p) {
    int tid = blockIdx.x * blockDim.x + threadIdx.x;
    int stride = gridDim.x * blockDim.x;
    for (int i = tid; i < NN_NODES; i += stride) counts[i] = 0;
    for (int i = tid; i < NN_GRAPHS * 7; i += stride) out[i] = 0.f;
    for (int i = tid; i < NN_NODES; i += stride) {
        float4 p;
        p.x = pos[3 * i]; p.y = pos[3 * i + 1]; p.z = pos[3 * i + 2]; p.w = 0.f;
        pos4[i] = p;
    }
    const float cT0f =  0.02830690f;
    const float cT1f = -0.02635231f;
    const float cT2f = -0.01634300f;
    const float cT3f =  0.01265893f;
    const float cT4f =  0.02041241f;
    for (int idx = tid; idx < 16 * 64 * 64; idx += stride) {
        int jj = idx & 63;
        int u  = (idx >> 6) & 63;
        int q  = idx >> 12;
        float v = 0.f;
        if (jj < 6) {
            v = cT0f * w2[(u * 16 + q) * 6 + jj];
        } else if (jj < 9) {
            if (u < 24) v = cT1f * w2[6144 + u * 16 + q];
        } else if (jj < 27) {
            int w = (jj - 9) % 6;
            if (u < 24) v = cT2f * w2[6528 + (u * 16 + q) * 6 + w];
        } else if (jj < 57) {
            int w = (jj - 27) % 6;
            if (u < 16) v = cT3f * w2[8832 + (u * 16 + q) * 6 + w];
        } else if (jj < 62) {
            if (u < 16) v = cT4f * w2[10368 + u * 16 + q];
        }
        w2p[idx] = v;
    }
}

// --------------------------- histogram -------------------------------------
__global__ __launch_bounds__(256) void k_hist(const int* __restrict__ edst,
                                              int* __restrict__ counts) {
    int e = blockIdx.x * blockDim.x + threadIdx.x;
    if (e < N_EDGES) atomicAdd(&counts[edst[e]], 1);
}

// ------------------ exclusive scan: wave-shuffle version -------------------
__global__ __launch_bounds__(1024) void k_scan(const int* __restrict__ counts,
                                               int* __restrict__ start,
                                               int* __restrict__ cursor) {
    __shared__ int wsum[16];
    __shared__ int carry;
    __shared__ int tot;
    int tid = threadIdx.x;
    int wave = tid >> 6;
    int lane = tid & 63;
    if (tid == 0) carry = 0;
    __syncthreads();
    for (int base = 0; base < NN_NODES; base += 1024) {
        int i = base + tid;
        int v = (i < NN_NODES) ? counts[i] : 0;
        int x = v;
#pragma unroll
        for (int off = 1; off < 64; off <<= 1) {
            int y = __shfl_up(x, off, 64);
            if (lane >= off) x += y;
        }
        if (lane == 63) wsum[wave] = x;
        __syncthreads();
        if (tid < 16) {
            int w = wsum[tid];
            int xx = w;
#pragma unroll
            for (int off = 1; off < 16; off <<= 1) {
                int y = __shfl_up(xx, off, 64);
                if (tid >= off) xx += y;
            }
            wsum[tid] = xx - w;            // exclusive wave offset
            if (tid == 15) tot = xx;       // chunk total
        }
        __syncthreads();
        int excl = carry + wsum[wave] + x - v;
        if (i < NN_NODES) {
            start[i] = excl;
            cursor[i] = excl;
        }
        __syncthreads();
        if (tid == 0) carry += tot;
        __syncthreads();
    }
    if (tid == 0) start[NN_NODES] = carry;   // = N_EDGES
}

// --------------------------- dst-CSR fill ----------------------------------
__global__ __launch_bounds__(256) void k_fill(const int* __restrict__ esrc,
                                              const int* __restrict__ edst,
                                              const int* __restrict__ zarr,
                                              int* __restrict__ cursor,
                                              int* __restrict__ csr) {
    int e = blockIdx.x * blockDim.x + threadIdx.x;
    if (e >= N_EDGES) return;
    int d = edst[e];
    int s = esrc[e];
    int q = 4 * zarr[s] + zarr[d];
    int p = atomicAdd(&cursor[d], 1);
    csr[p] = s | (q << 16) | ((d & 15) << 20);
}

// ------------- node_sh: edge-parallel, strided lanes, 16 nodes/block -------
__global__ __launch_bounds__(256) void k_nodesh(const float4* __restrict__ pos4,
                                                const int* __restrict__ start,
                                                const int* __restrict__ csr,
                                                float* __restrict__ node_sh) {
    __shared__ float ns[16][12];
    int t = threadIdx.x;
    if (t < 192) ns[t / 12][t % 12] = 0.f;
    __syncthreads();
    int nbase = blockIdx.x * 16;
    int e0 = start[nbase], e1 = start[nbase + 16];
    int lane = t & 63, wv = t >> 6;
    for (int idx = e0 + wv + lane * 4; idx < e1; idx += 256) {
        int pk = csr[idx];
        int s = pk & 0xFFFF;
        int r = (pk >> 20) & 15;
        float4 pd = pos4[nbase + r];
        float4 ps = pos4[s];
        float x = ps.x - pd.x;
        float y = ps.y - pd.y;
        float z = ps.z - pd.z;
        float B1[3], B2[5];
        sh_from_vec(x, y, z, B1, B2);
        float* nr = &ns[r][0];
        atomicAdd(nr + 0, 1.f);
        atomicAdd(nr + 1, B1[0]); atomicAdd(nr + 2, B1[1]); atomicAdd(nr + 3, B1[2]);
        atomicAdd(nr + 4, B2[0]); atomicAdd(nr + 5, B2[1]); atomicAdd(nr + 6, B2[2]);
        atomicAdd(nr + 7, B2[3]); atomicAdd(nr + 8, B2[4]);
    }
    __syncthreads();
    if (t < 144) {
        int r = t / 9, c = t % 9;
        const float inv_nn = 0.57735026918962576f;
        node_sh[(size_t)(nbase + r) * 12 + c] = ns[r][c] * inv_nn;
    }
}

// ---- phase-2 pass, statically instantiated (RB = 0 or 8, compile-time) ----
template<int RB>
__device__ __forceinline__ void phase2_pass(const float* __restrict__ Gl,
                                            float (* __restrict__ smid)[368],
                                            const float* __restrict__ w1,
                                            int zpack, int j) {
    const int zp = zpack >> (2 * RB);
    float acc[8] = {0.f, 0.f, 0.f, 0.f, 0.f, 0.f, 0.f, 0.f};
    if (j < 64) {
        int w = j;
        for (int q = 0; q < 16; q++) {
            float wa = w1[q * 64 + w];
            float wb = w1[2048 + q * 64 + w];
            float wc = w1[5248 + q * 64 + w];
            int zdq = q & 3;
            const float* Gq = Gl + (q >> 2) * 51;
#pragma unroll
            for (int r2 = 0; r2 < 8; r2++) {
                if (((zp >> (2 * r2)) & 3) == zdq) {
                    const float* gq = Gq + (RB + r2) * 204;
                    acc[r2] += gq[0] * wa + gq[12] * wb + gq[42] * wc;
                }
            }
        }
#pragma unroll
        for (int r2 = 0; r2 < 8; r2++)
            smid[RB + r2][j] = 0.33333333333333333f * acc[r2];
    } else if (j < 136) {
        int tt = j - 64, w = tt / 3, k = tt - 3 * w;
        for (int q = 0; q < 16; q++) {
            float wa = w1[3072 + q * 24 + w];
            float wb = w1[6272 + q * 24 + w];
            int zdq = q & 3;
            const float* Gq = Gl + (q >> 2) * 51;
#pragma unroll
            for (int r2 = 0; r2 < 8; r2++) {
                if (((zp >> (2 * r2)) & 3) == zdq) {
                    const float* gq = Gq + (RB + r2) * 204;
                    acc[r2] += gq[13 + k] * wa + gq[43 + k] * wb;
                }
            }
        }
#pragma unroll
        for (int r2 = 0; r2 < 8; r2++)
            smid[RB + r2][j] = 0.70710678118654752f * acc[r2];
    } else if (j < 208) {
        int tt = j - 136, w = tt / 3, k = tt - 3 * w;
        for (int q = 0; q < 16; q++) {
            float wa = w1[1024 + q * 24 + w];
            float wb = w1[1664 + q * 24 + w];
            float wc = w1[3712 + q * 24 + w];
            float wd = w1[4608 + q * 24 + w];
            int zdq = q & 3;
            const float* Gq = Gl + (q >> 2) * 51;
#pragma unroll
            for (int r2 = 0; r2 < 8; r2++) {
                if (((zp >> (2 * r2)) & 3) == zdq) {
                    const float* gq = Gq + (RB + r2) * 204;
                    acc[r2] += gq[1 + k] * wa + gq[9 + k] * wb +
                               gq[21 + k] * wc + gq[34 + k] * wd;
                }
            }
        }
#pragma unroll
        for (int r2 = 0; r2 < 8; r2++)
            smid[RB + r2][j] = 0.5f * acc[r2];
    } else if (j < 288) {
        int tt = j - 208, w = tt / 5, k = tt - 5 * w;
        for (int q = 0; q < 16; q++) {
            float wa = w1[1408 + q * 16 + w];
            float wb = w1[3456 + q * 16 + w];
            float wc = w1[4352 + q * 16 + w];
            float wd = w1[6656 + q * 16 + w];
            int zdq = q & 3;
            const float* Gq = Gl + (q >> 2) * 51;
#pragma unroll
            for (int r2 = 0; r2 < 8; r2++) {
                if (((zp >> (2 * r2)) & 3) == zdq) {
                    const float* gq = Gq + (RB + r2) * 204;
                    acc[r2] += gq[4 + k] * wa + gq[16 + k] * wb +
                               gq[29 + k] * wc + gq[46 + k] * wd;
                }
            }
        }
#pragma unroll
        for (int r2 = 0; r2 < 8; r2++)
            smid[RB + r2][j] = 0.64549722436790280f * acc[r2];
    } else if (j < 368) {
        int tt = j - 288, w = tt / 5, k = tt - 5 * w;
        for (int q = 0; q < 16; q++) {
            float wa = w1[4096 + q * 16 + w];
            float wb = w1[4992 + q * 16 + w];
            int zdq = q & 3;
            const float* Gq = Gl + (q >> 2) * 51;
#pragma unroll
            for (int r2 = 0; r2 < 8; r2++) {
                if (((zp >> (2 * r2)) & 3) == zdq) {
                    const float* gq = Gq + (RB + r2) * 204;
                    acc[r2] += gq[24 + k] * wa + gq[37 + k] * wb;
                }
            }
        }
#pragma unroll
        for (int r2 = 0; r2 < 8; r2++)
            smid[RB + r2][j] = 0.91287092917527690f * acc[r2];
    }
}

// ------- fused TP1 -> mid (LDS) -> TP2 tables; 16 nodes / 512 thr ----------
__global__ __launch_bounds__(512, 4) void k_mid(const float4* __restrict__ pos4,
                                                const float* __restrict__ node_sh,
                                                const int* __restrict__ start,
                                                const int* __restrict__ csr,
                                                const float* __restrict__ w1,
                                                const int* __restrict__ zarr,
                                                const float* __restrict__ w2p,
                                                float* __restrict__ tab) {
    __shared__ float Gl[16 * 204];         // [r][zs][51]
    __shared__ float smid[16][368];
    __shared__ int szl[16];
    __shared__ int zcnt[4];
    __shared__ int zlist[4][16];
    int t = threadIdx.x;
    int nbase = blockIdx.x * 16;
    for (int i = t; i < 16 * 204; i += 512) Gl[i] = 0.f;
    if (t < 16) szl[t] = zarr[nbase + t];
    else if (t < 20) zcnt[t - 16] = 0;
    __syncthreads();

    int e0 = start[nbase], e1 = start[nbase + 16];

    const float r3  = 0.57735026918962576f;
    const float r5  = 0.44721359549995794f;
    const float r6  = 0.40824829046386302f;
    const float r10 = 0.31622776601683794f;
    const float s30 = 0.18257418583505536f;
    const float rt3 = 1.7320508075688772f;
    const float c222 = 0.58554004376911990f;
    const float q6 = 0.40824829046386302f;
    const float h6 = 0.20412414523193151f;
    const float h2 = 0.35355339059327376f;
    const float r2c = 0.70710678118654752f;

    // Strided lane mapping: lanes of one wave touch edges 8 apart -> the
    // wave's 64 lanes span ~512 edges ~ all 16 nodes -> same-address atomic
    // depth drops ~16-32x -> ~2-4x.
    int lane0 = t & 63, wv0 = t >> 6;
    for (int idx = e0 + wv0 + lane0 * 8; idx < e1; idx += 512) {
        int pk = csr[idx];
        int s = pk & 0xFFFF;
        int zs = (pk >> 18) & 3;           // q>>2 = z_src
        int r = (pk >> 20) & 15;
        float4 pd = pos4[nbase + r];
        float4 ps = pos4[s];
        float x = ps.x - pd.x;
        float y = ps.y - pd.y;
        float z = ps.z - pd.z;
        float B1[3], B2[5];
        sh_from_vec(x, y, z, B1, B2);
        const float4 nv0 = *(const float4*)(node_sh + s * 12);
        const float4 nv1 = *(const float4*)(node_sh + s * 12 + 4);
        float a0 = nv0.x;
        float A1[3] = {nv0.y, nv0.z, nv0.w};
        float A2[5] = {nv1.x, nv1.y, nv1.z, nv1.w, node_sh[s * 12 + 8]};
        float* gr = Gl + r * 204 + zs * 51;

        atomicAdd(gr + 0, a0);
        atomicAdd(gr + 1, a0 * B1[0] * r3);
        atomicAdd(gr + 2, a0 * B1[1] * r3);
        atomicAdd(gr + 3, a0 * B1[2] * r3);
        atomicAdd(gr + 4, a0 * B2[0] * r5);
        atomicAdd(gr + 5, a0 * B2[1] * r5);
        atomicAdd(gr + 6, a0 * B2[2] * r5);
        atomicAdd(gr + 7, a0 * B2[3] * r5);
        atomicAdd(gr + 8, a0 * B2[4] * r5);
        atomicAdd(gr + 9,  A1[0] * r3);
        atomicAdd(gr + 10, A1[1] * r3);
        atomicAdd(gr + 11, A1[2] * r3);
        atomicAdd(gr + 12, -r3 * (A1[0] * B1[0] + A1[1] * B1[1] + A1[2] * B1[2]));
        atomicAdd(gr + 13, -r6 * (A1[1] * B1[2] - A1[2] * B1[1]));
        atomicAdd(gr + 14, -r6 * (A1[2] * B1[0] - A1[0] * B1[2]));
        atomicAdd(gr + 15, -r6 * (A1[0] * B1[1] - A1[1] * B1[0]));
        atomicAdd(gr + 16, r10 * (A1[0] * B1[2] + A1[2] * B1[0]));
        atomicAdd(gr + 17, r10 * (A1[0] * B1[1] + A1[1] * B1[0]));
        atomicAdd(gr + 18, s30 * (2.f * A1[1] * B1[1] - A1[0] * B1[0] - A1[2] * B1[2]));
        atomicAdd(gr + 19, r10 * (A1[1] * B1[2] + A1[2] * B1[1]));
        atomicAdd(gr + 20, r10 * (A1[2] * B1[2] - A1[0] * B1[0]));
        {
            float Byy = -B2[2] * q6 - B2[4] * r2c;
            float Bzz = 2.f * B2[2] * q6;
            float Bxx = -B2[2] * q6 + B2[4] * r2c;
            float Bxy = B2[0] * r2c;
            float Byz = B2[1] * r2c;
            float Bxz = B2[3] * r2c;
            atomicAdd(gr + 21, -r5 * (Byy * A1[0] + Byz * A1[1] + Bxy * A1[2]));
            atomicAdd(gr + 22, -r5 * (Byz * A1[0] + Bzz * A1[1] + Bxz * A1[2]));
            atomicAdd(gr + 23, -r5 * (Bxy * A1[0] + Bxz * A1[1] + Bxx * A1[2]));
        }
        atomicAdd(gr + 24, -s30 * (B2[1] * A1[0] - B2[3] * A1[2] + 2.f * B2[4] * A1[1]));
        atomicAdd(gr + 25, -s30 * (-B2[0] * A1[0] - rt3 * B2[2] * A1[2] + B2[3] * A1[1] - B2[4] * A1[2]));
        atomicAdd(gr + 26, -s30 * (rt3 * B2[1] * A1[2] - rt3 * B2[3] * A1[0]));
        atomicAdd(gr + 27, -s30 * (B2[0] * A1[2] - B2[1] * A1[1] + rt3 * B2[2] * A1[0] - B2[4] * A1[0]));
        atomicAdd(gr + 28, -s30 * (-2.f * B2[0] * A1[1] + B2[1] * A1[2] + B2[3] * A1[0]));
        atomicAdd(gr + 29, A2[0] * r5);
        atomicAdd(gr + 30, A2[1] * r5);
        atomicAdd(gr + 31, A2[2] * r5);
        atomicAdd(gr + 32, A2[3] * r5);
        atomicAdd(gr + 33, A2[4] * r5);
        {
            float Ayy = -A2[2] * q6 - A2[4] * r2c;
            float Azz = 2.f * A2[2] * q6;
            float Axx = -A2[2] * q6 + A2[4] * r2c;
            float Axy = A2[0] * r2c;
            float Ayz = A2[1] * r2c;
            float Axz = A2[3] * r2c;
            atomicAdd(gr + 34, -r5 * (Ayy * B1[0] + Ayz * B1[1] + Axy * B1[2]));
            atomicAdd(gr + 35, -r5 * (Ayz * B1[0] + Azz * B1[1] + Axz * B1[2]));
            atomicAdd(gr + 36, -r5 * (Axy * B1[0] + Axz * B1[1] + Axx * B1[2]));
        }
        atomicAdd(gr + 37, s30 * (A2[1] * B1[0] - A2[3] * B1[2] + 2.f * A2[4] * B1[1]));
        atomicAdd(gr + 38, s30 * (-A2[0] * B1[0] - rt3 * A2[2] * B1[2] + A2[3] * B1[1] - A2[4] * B1[2]));
        atomicAdd(gr + 39, s30 * (rt3 * A2[1] * B1[2] - rt3 * A2[3] * B1[0]));
        atomicAdd(gr + 40, s30 * (A2[0] * B1[2] - A2[1] * B1[1] + rt3 * A2[2] * B1[0] - A2[4] * B1[0]));
        atomicAdd(gr + 41, s30 * (-2.f * A2[0] * B1[1] + A2[1] * B1[2] + A2[3] * B1[0]));
        atomicAdd(gr + 42, r5 * (A2[0] * B2[0] + A2[1] * B2[1] + A2[2] * B2[2] +
                                 A2[3] * B2[3] + A2[4] * B2[4]));
        atomicAdd(gr + 43, s30 * (-A2[0] * B2[1] + A2[1] * B2[0] +
                                  rt3 * (A2[2] * B2[3] - A2[3] * B2[2]) +
                                  A2[3] * B2[4] - A2[4] * B2[3]));
        atomicAdd(gr + 44, s30 * (-2.f * A2[0] * B2[4] + 2.f * A2[4] * B2[0] -
                                  A2[1] * B2[3] + A2[3] * B2[1]));
        atomicAdd(gr + 45, s30 * (A2[0] * B2[3] - A2[3] * B2[0] +
                                  rt3 * (A2[1] * B2[2] - A2[2] * B2[1]) +
                                  A2[1] * B2[4] - A2[4] * B2[1]));
        atomicAdd(gr + 46, -c222 * (-q6 * (A2[0] * B2[2] + A2[2] * B2[0]) +
                                    h2 * (A2[1] * B2[3] + A2[3] * B2[1])));
        atomicAdd(gr + 47, -c222 * (h6 * (A2[1] * B2[2] + A2[2] * B2[1]) -
                                    h2 * (A2[1] * B2[4] + A2[4] * B2[1]) +
                                    h2 * (A2[0] * B2[3] + A2[3] * B2[0])));
        atomicAdd(gr + 48, -c222 * (q6 * (A2[2] * B2[2] - A2[0] * B2[0] - A2[4] * B2[4]) +
                                    h6 * (A2[1] * B2[1] + A2[3] * B2[3])));
        atomicAdd(gr + 49, -c222 * (h6 * (A2[3] * B2[2] + A2[2] * B2[3]) +
                                    h2 * (A2[3] * B2[4] + A2[4] * B2[3]) +
                                    h2 * (A2[0] * B2[1] + A2[1] * B2[0])));
        atomicAdd(gr + 50, -c222 * (-q6 * (A2[4] * B2[2] + A2[2] * B2[4]) +
                                    h2 * (A2[3] * B2[3] - A2[1] * B2[1])));
    }
    __syncthreads();

    // Pack all 16 node z-values into ONE scalar (2 bits each).
    int zpack = 0;
#pragma unroll
    for (int r2 = 0; r2 < 16; r2++)
        zpack |= __builtin_amdgcn_readfirstlane(szl[r2]) << (2 * r2);

    // Build per-z node lists (for phase-3 pairing).
    if (t < 16) {
        int zsv = (zpack >> (2 * t)) & 3;
        int p = atomicAdd(&zcnt[zsv], 1);
        zlist[zsv][p] = t;
    }

    // Phase 2: two STATIC passes (template RB = 0, 8).
    phase2_pass<0>(Gl, smid, w1, zpack, t);
    phase2_pass<8>(Gl, smid, w1, zpack, t);
    __syncthreads();

    // Phase 3: zd-fused, zs-paired.
    {
        int wave = t >> 6;
        int lane = t & 63;
        int mbase, mstride, ulim;
        if (lane < 6)       { mbase = 0;                mstride = 1; ulim = 64; }
        else if (lane < 9)  { mbase = 64 + (lane - 6);  mstride = 3; ulim = 24; }
        else if (lane < 27) { mbase = 136 + (lane - 9) / 6;  mstride = 3; ulim = 24; }
        else if (lane < 57) { mbase = 208 + (lane - 27) / 6; mstride = 5; ulim = 16; }
        else if (lane < 62) { mbase = 288 + (lane - 57);     mstride = 5; ulim = 16; }
        else                { mbase = 0;                mstride = 0; ulim = 1; }
        int ulim1 = ulim - 1;

        int c0 = zcnt[0], c1 = zcnt[1], c2 = zcnt[2], c3 = zcnt[3];
        int np0 = (c0 + 1) >> 1, np1 = (c1 + 1) >> 1;
        int np2 = (c2 + 1) >> 1, np3 = (c3 + 1) >> 1;
        int o1 = np0, o2 = o1 + np1, o3 = o2 + np2;
        int total = o3 + np3;

        for (int item = wave; item < total; item += 8) {
            int zsv, pi, cnt;
            if (item < o1)      { zsv = 0; pi = item;      cnt = c0; }
            else if (item < o2) { zsv = 1; pi = item - o1; cnt = c1; }
            else if (item < o3) { zsv = 2; pi = item - o2; cnt = c2; }
            else                { zsv = 3; pi = item - o3; cnt = c3; }
            int r0 = zlist[zsv][2 * pi];
            int i1 = 2 * pi + 1;
            int has2 = (i1 < cnt);
            int r1 = has2 ? zlist[zsv][i1] : r0;
            const float* mr0 = &smid[r0][0];
            const float* mr1 = &smid[r1][0];
            const float* wp = w2p + (size_t)(4 * zsv) * 4096 + lane;
            float a00 = 0.f, a01 = 0.f, a02 = 0.f, a03 = 0.f;
            float a10 = 0.f, a11 = 0.f, a12 = 0.f, a13 = 0.f;
#pragma unroll 4
            for (int u = 0; u < 64; u++) {
                int um = (u < ulim) ? u : ulim1;
                float w0 = wp[u * 64];
                float w1v = wp[4096 + u * 64];
                float w2v = wp[8192 + u * 64];
                float w3v = wp[12288 + u * 64];
                float m0 = mr0[mbase + mstride * um];
                float m1 = mr1[mbase + mstride * um];
                a00 += m0 * w0;  a01 += m0 * w1v;
                a02 += m0 * w2v; a03 += m0 * w3v;
                a10 += m1 * w0;  a11 += m1 * w1v;
                a12 += m1 * w2v; a13 += m1 * w3v;
            }
            size_t b0 = ((size_t)(nbase + r0) * 4) * 64 + lane;
            tab[b0] = a00; tab[b0 + 64] = a01;
            tab[b0 + 128] = a02; tab[b0 + 192] = a03;
            if (has2) {
                size_t b1 = ((size_t)(nbase + r1) * 4) * 64 + lane;
                tab[b1] = a10; tab[b1 + 64] = a11;
                tab[b1 + 128] = a12; tab[b1 + 192] = a13;
            }
        }
    }
}

// ---------------- TP2 + graph reduce: dst-major, 2-way unrolled ------------
__global__ __launch_bounds__(512, 8) void k_out(const float4* __restrict__ pos4,
                                                const int* __restrict__ zarr,
                                                const int* __restrict__ batch,
                                                const int* __restrict__ start,
                                                const int* __restrict__ csr,
                                                const float* __restrict__ tab,
                                                float* __restrict__ out) {
    int wave = threadIdx.x >> 6;
    int lane = threadIdx.x & 63;
    int n = blockIdx.x * 8 + wave;       // dst node
    float4 pd = pos4[n];
    int zd = zarr[n];
    int s0 = start[n], s1 = start[n + 1];

    int fsel, oidx;
    if (lane < 6)       { fsel = 0;                  oidx = lane + 1; }
    else if (lane < 9)  { fsel = 1 + (lane - 6);     oidx = 0; }
    else if (lane < 27) { fsel = 1 + (lane - 9) / 6; oidx = (lane - 9) % 6 + 1; }
    else if (lane < 57) { fsel = 4 + (lane - 27) / 6; oidx = (lane - 27) % 6 + 1; }
    else if (lane < 62) { fsel = 4 + (lane - 57);    oidx = 0; }
    else                { fsel = -1;                 oidx = 7; }
    float f0 = (fsel == 0) ? 1.f : 0.f;
    float f1 = (fsel == 1) ? 1.f : 0.f;
    float f2 = (fsel == 2) ? 1.f : 0.f;
    float f3 = (fsel == 3) ? 1.f : 0.f;
    float f4 = (fsel == 4) ? 1.f : 0.f;
    float f5 = (fsel == 5) ? 1.f : 0.f;
    float f6 = (fsel == 6) ? 1.f : 0.f;
    float f7 = (fsel == 7) ? 1.f : 0.f;
    float f8 = (fsel == 8) ? 1.f : 0.f;

    float acc = 0.f;
    int idx = s0;
    for (; idx + 1 < s1; idx += 2) {
        int pkA = __builtin_amdgcn_readfirstlane(csr[idx]);
        int pkB = __builtin_amdgcn_readfirstlane(csr[idx + 1]);
        int sA = pkA & 0xFFFF;
        int sB = pkB & 0xFFFF;
        float TA = tab[((size_t)sA * 4 + zd) * 64 + lane];
        float TB = tab[((size_t)sB * 4 + zd) * 64 + lane];
        float4 psA = pos4[sA];
        float4 psB = pos4[sB];
        float xA = psA.x - pd.x, yA = psA.y - pd.y, zA = psA.z - pd.z;
        float xB = psB.x - pd.x, yB = psB.y - pd.y, zB = psB.z - pd.z;
        float B1A[3], B2A[5], B1B[3], B2B[5];
        sh_from_vec(xA, yA, zA, B1A, B2A);
        sh_from_vec(xB, yB, zB, B1B, B2B);
        float fA = f0 + f1 * B1A[0] + f2 * B1A[1] + f3 * B1A[2]
                 + f4 * B2A[0] + f5 * B2A[1] + f6 * B2A[2]
                 + f7 * B2A[3] + f8 * B2A[4];
        float fB = f0 + f1 * B1B[0] + f2 * B1B[1] + f3 * B1B[2]
                 + f4 * B2B[0] + f5 * B2B[1] + f6 * B2B[2]
                 + f7 * B2B[3] + f8 * B2B[4];
        acc += TA * fA + TB * fB;
    }
    if (idx < s1) {
        int pk = __builtin_amdgcn_readfirstlane(csr[idx]);
        int s = pk & 0xFFFF;
        float T = tab[((size_t)s * 4 + zd) * 64 + lane];
        float4 ps = pos4[s];
        float x = ps.x - pd.x, y = ps.y - pd.y, z = ps.z - pd.z;
        float B1[3], B2[5];
        sh_from_vec(x, y, z, B1, B2);
        float factor = f0 + f1 * B1[0] + f2 * B1[1] + f3 * B1[2]
                     + f4 * B2[0] + f5 * B2[1] + f6 * B2[2]
                     + f7 * B2[3] + f8 * B2[4];
        acc += T * factor;
    }

    float ov[7];
#pragma unroll
    for (int w = 0; w < 7; w++) ov[w] = (oidx == w) ? acc : 0.f;
#pragma unroll
    for (int off = 32; off > 0; off >>= 1)
#pragma unroll
        for (int w = 0; w < 7; w++) ov[w] += __shfl_down(ov[w], off, 64);
    if (lane == 0) {
        float* og = out + batch[n] * 7;
#pragma unroll
        for (int w = 0; w < 7; w++) atomicAdd(og + w, ov[w]);
    }
}

// ---------------------------------------------------------------------------
extern "C" void kernel_launch(void* const* d_in, const int* in_sizes, int n_in,
                              void* d_out, int out_size, void* d_ws, size_t ws_size,
                              hipStream_t stream) {
    const float* pos  = (const float*)d_in[0];
    const int*   z    = (const int*)d_in[1];
    const int*   bat  = (const int*)d_in[2];
    const int*   esrc = (const int*)d_in[3];
    const int*   edst = (const int*)d_in[4];
    const float* w1   = (const float*)d_in[5];
    const float* w2   = (const float*)d_in[6];
    float* out = (float*)d_out;

    int*   wsI = (int*)d_ws;
    float* wsF = (float*)d_ws;
    int* counts  = wsI + 0;
    int* start   = wsI + 32768;
    int* cursor  = wsI + 65536;
    int* csr     = wsI + 98304;
    float4* pos4   = (float4*)(wsF + 425984);
    float* node_sh = wsF + 524288;
    float* w2p     = wsF + 786432;
    float* tab     = wsF + 1048576;

    k_zero<<<128, 256, 0, stream>>>(pos, w2, counts, out, pos4, w2p);
    k_hist<<<(N_EDGES + 255) / 256, 256, 0, stream>>>(edst, counts);
    k_scan<<<1, 1024, 0, stream>>>(counts, start, cursor);
    k_fill<<<(N_EDGES + 255) / 256, 256, 0, stream>>>(esrc, edst, z, cursor, csr);
    k_nodesh<<<NN_NODES / 16, 256, 0, stream>>>(pos4, start, csr, node_sh);
    k_mid<<<NN_NODES / 16, 512, 0, stream>>>(pos4, node_sh, start, csr, w1, z, w2p, tab);
    k_out<<<NN_NODES / 8, 512, 0, stream>>>(pos4, z, bat, start, csr, tab, out);
}